// Round 1
// baseline (1742.455 us; speedup 1.0000x reference)
//
#include <hip/hip_runtime.h>
#include <hip/hip_fp16.h>
#include <math.h>

typedef _Float16 f16;
typedef _Float16 f16x4 __attribute__((ext_vector_type(4)));
typedef _Float16 f16x8 __attribute__((ext_vector_type(8)));
typedef float f32x4 __attribute__((ext_vector_type(4)));
typedef unsigned long long u64;

// async global->LDS, 16B per lane; LDS dest must be wave-uniform base (HW adds lane*16)
#define GLD16(g, s) __builtin_amdgcn_global_load_lds( \
    (const __attribute__((address_space(1))) void*)(g), \
    (__attribute__((address_space(3))) void*)(s), 16, 0, 0)

// ---------------------------------------------------------------------------
// split fp32 -> (hi, lo) f16 pair, pre-scaled by `scale` (=256) so lo stays
// in f16-normal range. hi+lo represents scale*x with ~2^-22 relative error.
// ---------------------------------------------------------------------------
__global__ __launch_bounds__(256) void split_kernel(const float* __restrict__ src,
                                                    f16* __restrict__ hi,
                                                    f16* __restrict__ lo,
                                                    long n4, float scale) {
  long stride = (long)gridDim.x * blockDim.x;
  for (long i = (long)blockIdx.x * blockDim.x + threadIdx.x; i < n4; i += stride) {
    float4 v = ((const float4*)src)[i];
    f16x4 h, l;
    float e0 = v.x * scale; f16 h0 = (f16)e0; h[0] = h0; l[0] = (f16)(e0 - (float)h0);
    float e1 = v.y * scale; f16 h1 = (f16)e1; h[1] = h1; l[1] = (f16)(e1 - (float)h1);
    float e2 = v.z * scale; f16 h2 = (f16)e2; h[2] = h2; l[2] = (f16)(e2 - (float)h2);
    float e3 = v.w * scale; f16 h3 = (f16)e3; h[3] = h3; l[3] = (f16)(e3 - (float)h3);
    ((f16x4*)hi)[i] = h;
    ((f16x4*)lo)[i] = l;
  }
}

// ---------------------------------------------------------------------------
// Split-precision GEMM: C[m][n] = sum_k A[m,k]*B[n,k]  (both K-major, B^T form)
// A = (A1+A2)/256, B = (B1+B2)/256 in f16; 4 MFMA products per fragment.
// EPI=1: out = relu(acc/65536 + bias), store 256*out as f16 hi/lo (feeds GEMM2)
// EPI=2: out = relu(acc/65536 + bias), store fp32
// m97 structure: 128x128 tile, BK=32, 4 waves (2x2), 4x4 16x16 frags per wave.
// ---------------------------------------------------------------------------
template<int EPI>
__global__ __launch_bounds__(256) void gemm_split(
    const f16* __restrict__ A1, const f16* __restrict__ A2,
    const f16* __restrict__ B1, const f16* __restrict__ B2,
    const float* __restrict__ bias,
    void* __restrict__ out1, void* __restrict__ out2,
    const int M, const int K) {
  __shared__ f16 sA1[4096], sA2[4096], sB1[4096], sB2[4096];  // 4 x 8KB
  const int tid = threadIdx.x;
  const int lane = tid & 63;
  const int wid = tid >> 6;
  const int wr = wid >> 1, wcol = wid & 1;
  const int m0 = blockIdx.y * 128;
  const int n0 = blockIdx.x * 128;

  f32x4 acc[4][4];
#pragma unroll
  for (int m = 0; m < 4; ++m)
#pragma unroll
    for (int n = 0; n < 4; ++n) acc[m][n] = (f32x4){0.f, 0.f, 0.f, 0.f};

  // staging: element-block e = q*256 + tid covers LDS elements e*8..e*8+7
  // -> tile row = e/4, k-offset = (e%4)*8.  Per-lane GLOBAL addr, uniform LDS base.
  const int rq = tid >> 2;           // 0..63
  const int ko = (tid & 3) * 8;
  int ra0 = m0 + rq;       if (ra0 > M - 1) ra0 = M - 1;  // clamp M-edge rows
  int ra1 = m0 + 64 + rq;  if (ra1 > M - 1) ra1 = M - 1;
  const int rb0 = n0 + rq, rb1 = n0 + 64 + rq;            // N=1024 always full
  const f16* gA1q0 = A1 + (size_t)ra0 * K + ko;
  const f16* gA1q1 = A1 + (size_t)ra1 * K + ko;
  const f16* gA2q0 = A2 + (size_t)ra0 * K + ko;
  const f16* gA2q1 = A2 + (size_t)ra1 * K + ko;
  const f16* gB1q0 = B1 + (size_t)rb0 * K + ko;
  const f16* gB1q1 = B1 + (size_t)rb1 * K + ko;
  const f16* gB2q0 = B2 + (size_t)rb0 * K + ko;
  const f16* gB2q1 = B2 + (size_t)rb1 * K + ko;
  const int du = wid * 512;          // wave-uniform LDS element base (q=0); q=1 adds 2048

  const int arow = wr * 64 + (lane & 15);
  const int brow = wcol * 64 + (lane & 15);
  const int kc = (lane >> 4) * 8;

  for (int kt = 0; kt < K; kt += 32) {
    GLD16(gA1q0 + kt, sA1 + du);
    GLD16(gA1q1 + kt, sA1 + 2048 + du);
    GLD16(gA2q0 + kt, sA2 + du);
    GLD16(gA2q1 + kt, sA2 + 2048 + du);
    GLD16(gB1q0 + kt, sB1 + du);
    GLD16(gB1q1 + kt, sB1 + 2048 + du);
    GLD16(gB2q0 + kt, sB2 + du);
    GLD16(gB2q1 + kt, sB2 + 2048 + du);
    __syncthreads();  // drains vmcnt: LDS tiles ready

    f16x8 a1[4], a2[4], b1[4], b2[4];
#pragma unroll
    for (int m = 0; m < 4; ++m) {
      a1[m] = *(const f16x8*)&sA1[(arow + m * 16) * 32 + kc];
      a2[m] = *(const f16x8*)&sA2[(arow + m * 16) * 32 + kc];
    }
#pragma unroll
    for (int n = 0; n < 4; ++n) {
      b1[n] = *(const f16x8*)&sB1[(brow + n * 16) * 32 + kc];
      b2[n] = *(const f16x8*)&sB2[(brow + n * 16) * 32 + kc];
    }
#pragma unroll
    for (int m = 0; m < 4; ++m)
#pragma unroll
      for (int n = 0; n < 4; ++n) {
        acc[m][n] = __builtin_amdgcn_mfma_f32_16x16x32_f16(a1[m], b1[n], acc[m][n], 0, 0, 0);
        acc[m][n] = __builtin_amdgcn_mfma_f32_16x16x32_f16(a2[m], b1[n], acc[m][n], 0, 0, 0);
        acc[m][n] = __builtin_amdgcn_mfma_f32_16x16x32_f16(a1[m], b2[n], acc[m][n], 0, 0, 0);
        acc[m][n] = __builtin_amdgcn_mfma_f32_16x16x32_f16(a2[m], b2[n], acc[m][n], 0, 0, 0);
      }
    __syncthreads();  // protect LDS before next stage
  }

  // epilogue: D mapping col=lane&15, row=4*(lane>>4)+j  (m89-verified)
  const int crow = m0 + wr * 64 + 4 * (lane >> 4);
  const int ccol0 = n0 + wcol * 64 + (lane & 15);
#pragma unroll
  for (int n = 0; n < 4; ++n) {
    const int col = ccol0 + n * 16;
    const float bv = bias[col];
#pragma unroll
    for (int m = 0; m < 4; ++m) {
#pragma unroll
      for (int j = 0; j < 4; ++j) {
        const int row = crow + m * 16 + j;
        if (row < M) {
          float v = acc[m][n][j] * (1.0f / 65536.0f) + bv;
          v = fmaxf(v, 0.0f);
          if (EPI == 1) {
            float sv = v * 256.0f;
            f16 hh = (f16)sv;
            ((f16*)out1)[(size_t)row * 1024 + col] = hh;
            ((f16*)out2)[(size_t)row * 1024 + col] = (f16)(sv - (float)hh);
          } else {
            ((float*)out1)[(size_t)row * 1024 + col] = v;
          }
        }
      }
    }
  }
}

// ---------------------------------------------------------------------------
// Final head: c/r dots (fp32), argmax/scores, per-class delta, box decode+clip
// One wave per ROI row.
// ---------------------------------------------------------------------------
__device__ __forceinline__ float dot4f(float4 a, float4 b) {
  return a.x * b.x + a.y * b.y + a.z * b.z + a.w * b.w;
}

__global__ __launch_bounds__(256) void head_final(
    const float* __restrict__ v7,
    const float* __restrict__ wc, const float* __restrict__ bc,
    const float* __restrict__ wr, const float* __restrict__ br,
    const float* __restrict__ rois,
    float* __restrict__ outScores, float* __restrict__ outClasses,
    float* __restrict__ outBoxes,
    float* __restrict__ smask, float* __restrict__ wsbox, int* __restrict__ wsval) {
  const int gw = (blockIdx.x * 256 + threadIdx.x) >> 6;
  const int lane = threadIdx.x & 63;
  if (gw >= 8000) return;

  const float4* vr = (const float4*)(v7 + (size_t)gw * 1024);
  float4 x0 = vr[lane], x1 = vr[64 + lane], x2 = vr[128 + lane], x3 = vr[192 + lane];

  float s[20];
#pragma unroll
  for (int o = 0; o < 20; ++o) {
    const float* wrow = (o < 4) ? (wc + o * 1024) : (wr + (o - 4) * 1024);
    const float4* w4 = (const float4*)wrow;
    float a = dot4f(x0, w4[lane]) + dot4f(x1, w4[64 + lane]) +
              dot4f(x2, w4[128 + lane]) + dot4f(x3, w4[192 + lane]);
#pragma unroll
    for (int off = 32; off >= 1; off >>= 1) a += __shfl_xor(a, off);
    s[o] = a + ((o < 4) ? bc[o] : br[o - 4]);
  }

  // argmax (first-max semantics, strict >)
  float best = s[0]; int cls = 0;
  if (s[1] > best) { best = s[1]; cls = 1; }
  if (s[2] > best) { best = s[2]; cls = 2; }
  if (s[3] > best) { best = s[3]; cls = 3; }

  float d0, d1, d2, d3;  // constant indices only (avoid scratch)
  if      (cls == 0) { d0 = s[4];  d1 = s[5];  d2 = s[6];  d3 = s[7];  }
  else if (cls == 1) { d0 = s[8];  d1 = s[9];  d2 = s[10]; d3 = s[11]; }
  else if (cls == 2) { d0 = s[12]; d1 = s[13]; d2 = s[14]; d3 = s[15]; }
  else               { d0 = s[16]; d1 = s[17]; d2 = s[18]; d3 = s[19]; }

  float4 rb = ((const float4*)rois)[gw];
  float w = rb.z - rb.x, h = rb.w - rb.y;
  float cx = rb.x + 0.5f * w, cy = rb.y + 0.5f * h;
  float pcx = cx + d0 * 0.1f * w;
  float pcy = cy + d1 * 0.1f * h;
  float pw = expf(d2 * 0.2f) * w;
  float ph = expf(d3 * 0.2f) * h;
  float bx0 = fminf(fmaxf(pcx - 0.5f * pw, 0.f), 512.f);
  float by0 = fminf(fmaxf(pcy - 0.5f * ph, 0.f), 512.f);
  float bx1 = fminf(fmaxf(pcx + 0.5f * pw, 0.f), 512.f);
  float by1 = fminf(fmaxf(pcy + 0.5f * ph, 0.f), 512.f);

  if (lane == 0) {
    outScores[gw] = best;
    outClasses[gw] = (float)cls;
    outBoxes[gw * 4 + 0] = bx0;
    outBoxes[gw * 4 + 1] = by0;
    outBoxes[gw * 4 + 2] = bx1;
    outBoxes[gw * 4 + 3] = by1;
    int valid = (cls != 3);
    smask[gw] = valid ? best : -INFINITY;
    wsval[gw] = valid;
    float4 bb; bb.x = bx0; bb.y = by0; bb.z = bx1; bb.w = by1;
    ((float4*)wsbox)[gw] = bb;
  }
}

// ---------------------------------------------------------------------------
// Stable descending rank (== argsort(-s) position), then scatter to sorted arrays
// ---------------------------------------------------------------------------
__global__ __launch_bounds__(256) void rank_kernel(
    const float* __restrict__ smask, const float* __restrict__ bx,
    const int* __restrict__ valid,
    int* __restrict__ order, float* __restrict__ sboxes, int* __restrict__ svalid) {
  __shared__ __align__(16) float sS[8000];
  const int tid = threadIdx.x;
  for (int i = tid; i < 8000; i += 256) sS[i] = smask[i];
  __syncthreads();
  const int i = blockIdx.x * 256 + tid;
  if (i >= 8000) return;
  const float si = sS[i];
  int cnt = 0;
  const float4* s4p = (const float4*)sS;
  for (int j4 = 0; j4 < 2000; ++j4) {
    float4 s4 = s4p[j4];
    int jb = j4 * 4;
    cnt += (s4.x > si) || (s4.x == si && (jb + 0) < i);
    cnt += (s4.y > si) || (s4.y == si && (jb + 1) < i);
    cnt += (s4.z > si) || (s4.z == si && (jb + 2) < i);
    cnt += (s4.w > si) || (s4.w == si && (jb + 3) < i);
  }
  order[cnt] = i;
  svalid[cnt] = valid[i];
  ((float4*)sboxes)[cnt] = ((const float4*)bx)[i];
}

// ---------------------------------------------------------------------------
// Suppression bitmask matrix in SORTED order: M[row][w] bit j = (IoU>0.2 && col>row)
// row stride padded to 128 u64. Upper triangle only.
// ---------------------------------------------------------------------------
__global__ void iou_matrix(const float* __restrict__ sboxes, u64* __restrict__ M) {
  const int t = blockIdx.y, w = blockIdx.x;
  if (w < t) return;
  const int lane = threadIdx.x;
  __shared__ __align__(16) float cb[64 * 4];
  ((float4*)cb)[lane] = ((const float4*)sboxes)[w * 64 + lane];
  __syncthreads();
  const int ri = t * 64 + lane;
  float4 rb = ((const float4*)sboxes)[ri];
  const float ra = (rb.z - rb.x) * (rb.w - rb.y);
  u64 bits = 0;
  for (int j = 0; j < 64; ++j) {
    float4 c = ((float4*)cb)[j];
    float x1 = fmaxf(rb.x, c.x), y1 = fmaxf(rb.y, c.y);
    float x2 = fminf(rb.z, c.z), y2 = fminf(rb.w, c.w);
    float inter = fmaxf(x2 - x1, 0.f) * fmaxf(y2 - y1, 0.f);
    float ca = (c.z - c.x) * (c.w - c.y);
    float iou = inter / (ra + ca - inter + 1e-8f);
    int gc = w * 64 + j;
    if (iou > 0.2f && gc > ri) bits |= (1ULL << j);
  }
  M[(size_t)ri * 128 + w] = bits;
}

// ---------------------------------------------------------------------------
// Sequential greedy NMS scan over the bitmask matrix. Single block.
// Per 64-box tile: wave-0 register closure (exact sequential semantics),
// then parallel OR of kept rows into the 125-word accumulator.
// ---------------------------------------------------------------------------
__global__ __launch_bounds__(128) void nms_scan(
    const u64* __restrict__ M, const int* __restrict__ order,
    const int* __restrict__ svalid, float* __restrict__ outKeep) {
  __shared__ u64 acc[125];
  __shared__ u64 rshare;
  const int tid = threadIdx.x;
  for (int w = tid; w < 125; w += 128) acc[w] = 0;
  __syncthreads();

  for (int t = 0; t < 125; ++t) {
    if (tid < 64) {  // wave 0 entire: shfl-safe
      u64 myrow = M[(size_t)(t * 64 + tid) * 128 + t];  // intra-tile word
      u64 r = acc[t];
      for (int i = 0; i < 64; ++i) {
        unsigned rlo = (unsigned)__shfl((int)(unsigned)myrow, i);
        unsigned rhi = (unsigned)__shfl((int)(unsigned)(myrow >> 32), i);
        u64 rowi = ((u64)rhi << 32) | (u64)rlo;
        if (!((r >> i) & 1ULL)) r |= rowi;
      }
      if (tid == 0) { acc[t] = r; rshare = r; }
    }
    __syncthreads();
    const u64 rr = rshare;
    const int w = t + 1 + tid;
    if (w < 125) {
      u64 a = acc[w];
      u64 kept = ~rr;  // bit set => kept box in tile t
      while (kept) {
        int i = __builtin_ctzll(kept);
        kept &= kept - 1;
        a |= M[(size_t)(t * 64 + i) * 128 + w];
      }
      acc[w] = a;
    }
    __syncthreads();
  }

  for (int p = tid; p < 8000; p += 128) {
    int removed = (int)((acc[p >> 6] >> (p & 63)) & 1ULL);
    float kv = (!removed && svalid[p]) ? 1.0f : 0.0f;
    outKeep[order[p]] = kv;
  }
}

// ---------------------------------------------------------------------------
extern "C" void kernel_launch(void* const* d_in, const int* in_sizes, int n_in,
                              void* d_out, int out_size, void* d_ws, size_t ws_size,
                              hipStream_t stream) {
  const float* F    = (const float*)d_in[0];
  const float* ROIS = (const float*)d_in[1];
  const float* W6   = (const float*)d_in[2];
  const float* B6   = (const float*)d_in[3];
  const float* W7   = (const float*)d_in[4];
  const float* B7   = (const float*)d_in[5];
  const float* WC   = (const float*)d_in[6];
  const float* BC   = (const float*)d_in[7];
  const float* WR   = (const float*)d_in[8];
  const float* BR   = (const float*)d_in[9];

  const size_t N = 8000, D = 12544, H = 1024;
  char* ws = (char*)d_ws;
  size_t off = 0;
  auto alloc = [&](size_t bytes) -> void* {
    void* p = (void*)(ws + off);
    off += (bytes + 255) & ~(size_t)255;
    return p;
  };
  f16*   A1    = (f16*)alloc(N * D * 2);
  f16*   A2    = (f16*)alloc(N * D * 2);
  f16*   B1w   = (f16*)alloc(H * D * 2);
  f16*   B2w   = (f16*)alloc(H * D * 2);
  f16*   V61   = (f16*)alloc(N * H * 2);
  f16*   V62   = (f16*)alloc(N * H * 2);
  f16*   W71   = (f16*)alloc(H * H * 2);
  f16*   W72   = (f16*)alloc(H * H * 2);
  float* V7    = (float*)alloc(N * H * 4);
  float* SMASK = (float*)alloc(N * 4);
  float* WSBOX = (float*)alloc(N * 16);
  int*   WSVAL = (int*)alloc(N * 4);
  int*   ORDER = (int*)alloc(N * 4);
  float* SBOX  = (float*)alloc(N * 16);
  int*   SVAL  = (int*)alloc(N * 4);
  u64*   MM    = (u64*)alloc(N * 128 * 8);

  float* outScores  = (float*)d_out;
  float* outClasses = (float*)d_out + 8000;
  float* outBoxes   = (float*)d_out + 16000;
  float* outKeep    = (float*)d_out + 48000;

  split_kernel<<<2048, 256, 0, stream>>>(F, A1, A2, (long)(N * D / 4), 256.0f);
  split_kernel<<<1024, 256, 0, stream>>>(W6, B1w, B2w, (long)(H * D / 4), 256.0f);
  split_kernel<<<256, 256, 0, stream>>>(W7, W71, W72, (long)(H * H / 4), 256.0f);

  gemm_split<1><<<dim3(8, 63), 256, 0, stream>>>(A1, A2, B1w, B2w, B6, V61, V62, 8000, 12544);
  gemm_split<2><<<dim3(8, 63), 256, 0, stream>>>(V61, V62, W71, W72, B7, V7, nullptr, 8000, 1024);

  head_final<<<2000, 256, 0, stream>>>(V7, WC, BC, WR, BR, ROIS,
                                       outScores, outClasses, outBoxes,
                                       SMASK, WSBOX, WSVAL);
  rank_kernel<<<32, 256, 0, stream>>>(SMASK, WSBOX, WSVAL, ORDER, SBOX, SVAL);
  iou_matrix<<<dim3(125, 125), 64, 0, stream>>>(SBOX, MM);
  nms_scan<<<1, 128, 0, stream>>>(MM, ORDER, SVAL, outKeep);
}

// Round 2
// 1560.000 us; speedup vs baseline: 1.1170x; 1.1170x over previous
//
#include <hip/hip_runtime.h>
#include <hip/hip_fp16.h>
#include <math.h>

typedef _Float16 f16;
typedef _Float16 f16x4 __attribute__((ext_vector_type(4)));
typedef _Float16 f16x8 __attribute__((ext_vector_type(8)));
typedef float f32x4 __attribute__((ext_vector_type(4)));
typedef unsigned long long u64;

// async global->LDS, 16B per lane; LDS dest must be wave-uniform base (HW adds lane*16)
#define GLD16(g, s) __builtin_amdgcn_global_load_lds( \
    (const __attribute__((address_space(1))) void*)(g), \
    (__attribute__((address_space(3))) void*)(s), 16, 0, 0)

// ---------------------------------------------------------------------------
// split fp32 -> (hi, lo) f16 pair, pre-scaled by `scale` (=256) so lo stays
// in f16-normal range. hi+lo represents scale*x with ~2^-22 relative error.
// ---------------------------------------------------------------------------
__global__ __launch_bounds__(256) void split_kernel(const float* __restrict__ src,
                                                    f16* __restrict__ hi,
                                                    f16* __restrict__ lo,
                                                    long n4, float scale) {
  long stride = (long)gridDim.x * blockDim.x;
  for (long i = (long)blockIdx.x * blockDim.x + threadIdx.x; i < n4; i += stride) {
    float4 v = ((const float4*)src)[i];
    f16x4 h, l;
    float e0 = v.x * scale; f16 h0 = (f16)e0; h[0] = h0; l[0] = (f16)(e0 - (float)h0);
    float e1 = v.y * scale; f16 h1 = (f16)e1; h[1] = h1; l[1] = (f16)(e1 - (float)h1);
    float e2 = v.z * scale; f16 h2 = (f16)e2; h[2] = h2; l[2] = (f16)(e2 - (float)h2);
    float e3 = v.w * scale; f16 h3 = (f16)e3; h[3] = h3; l[3] = (f16)(e3 - (float)h3);
    ((f16x4*)hi)[i] = h;
    ((f16x4*)lo)[i] = l;
  }
}

// ---------------------------------------------------------------------------
// Split-precision GEMM, 3-product (hi*hi + lo*hi + hi*lo; lo*lo ~2^-22 dropped)
// 128x128 tile, BK=32, 4 waves, double-buffered LDS, chunk-XOR swizzle:
//   LDS[row][chunk_pos] holds global chunk (chunk_pos ^ ((row>>1)&3))
//   (pre-swizzled GLOBAL source addr; linear global_load_lds dest; swizzled read)
// ---------------------------------------------------------------------------
template<int EPI>
__global__ __launch_bounds__(256) void gemm_split(
    const f16* __restrict__ A1, const f16* __restrict__ A2,
    const f16* __restrict__ B1, const f16* __restrict__ B2,
    const float* __restrict__ bias,
    void* __restrict__ out1, void* __restrict__ out2,
    const int M, const int K) {
  __shared__ f16 sA1[2][4096], sA2[2][4096], sB1[2][4096], sB2[2][4096];  // 64 KB
  const int tid = threadIdx.x;
  const int lane = tid & 63;
  const int wid = tid >> 6;
  const int wr = wid >> 1, wcol = wid & 1;
  const int m0 = blockIdx.y * 128;
  const int n0 = blockIdx.x * 128;

  f32x4 acc[4][4];
#pragma unroll
  for (int m = 0; m < 4; ++m)
#pragma unroll
    for (int n = 0; n < 4; ++n) acc[m][n] = (f32x4){0.f, 0.f, 0.f, 0.f};

  // staging: LDS block e = q*256+tid -> (row=e>>2, chunk_pos=e&3).
  // global chunk to fetch = chunk_pos ^ ((row>>1)&3)  (XOR involution)
  const int rq = tid >> 2;                                  // 0..63
  const int cg = (((tid & 3) ^ ((rq >> 1) & 3)) * 8);       // swizzled k-offset (elems)
  int ra0 = m0 + rq;       if (ra0 > M - 1) ra0 = M - 1;    // clamp M-edge rows
  int ra1 = m0 + 64 + rq;  if (ra1 > M - 1) ra1 = M - 1;
  const int rb0 = n0 + rq, rb1 = n0 + 64 + rq;              // N=1024 always full
  const f16* gA1q0 = A1 + (size_t)ra0 * K + cg;
  const f16* gA1q1 = A1 + (size_t)ra1 * K + cg;
  const f16* gA2q0 = A2 + (size_t)ra0 * K + cg;
  const f16* gA2q1 = A2 + (size_t)ra1 * K + cg;
  const f16* gB1q0 = B1 + (size_t)rb0 * K + cg;
  const f16* gB1q1 = B1 + (size_t)rb1 * K + cg;
  const f16* gB2q0 = B2 + (size_t)rb0 * K + cg;
  const f16* gB2q1 = B2 + (size_t)rb1 * K + cg;
  const int du = wid * 512;  // wave-uniform LDS element base (q=0); q=1 adds 2048

  const int arow = wr * 64 + (lane & 15);
  const int brow = wcol * 64 + (lane & 15);
  // swizzled read chunk: ((row+16m)>>1)&3 is m-independent
  const int kcA = (((lane >> 4) ^ ((arow >> 1) & 3)) * 8);
  const int kcB = (((lane >> 4) ^ ((brow >> 1) & 3)) * 8);

  const int nt = K / 32;

#define STAGE(buf, kt)                              \
  do {                                              \
    GLD16(gA1q0 + (kt), &sA1[buf][du]);             \
    GLD16(gA1q1 + (kt), &sA1[buf][2048 + du]);      \
    GLD16(gA2q0 + (kt), &sA2[buf][du]);             \
    GLD16(gA2q1 + (kt), &sA2[buf][2048 + du]);      \
    GLD16(gB1q0 + (kt), &sB1[buf][du]);             \
    GLD16(gB1q1 + (kt), &sB1[buf][2048 + du]);      \
    GLD16(gB2q0 + (kt), &sB2[buf][du]);             \
    GLD16(gB2q1 + (kt), &sB2[buf][2048 + du]);      \
  } while (0)

  STAGE(0, 0);
  __syncthreads();  // drains vmcnt: buf0 ready
  int cur = 0;

  for (int t = 0; t < nt; ++t) {
    if (t + 1 < nt) STAGE(cur ^ 1, (t + 1) * 32);  // prefetch BEFORE compute

    f16x8 a1[4], a2[4], b1[4], b2[4];
#pragma unroll
    for (int m = 0; m < 4; ++m) {
      a1[m] = *(const f16x8*)&sA1[cur][(arow + m * 16) * 32 + kcA];
      a2[m] = *(const f16x8*)&sA2[cur][(arow + m * 16) * 32 + kcA];
    }
#pragma unroll
    for (int n = 0; n < 4; ++n) {
      b1[n] = *(const f16x8*)&sB1[cur][(brow + n * 16) * 32 + kcB];
      b2[n] = *(const f16x8*)&sB2[cur][(brow + n * 16) * 32 + kcB];
    }
#pragma unroll
    for (int m = 0; m < 4; ++m)
#pragma unroll
      for (int n = 0; n < 4; ++n) {
        acc[m][n] = __builtin_amdgcn_mfma_f32_16x16x32_f16(a1[m], b1[n], acc[m][n], 0, 0, 0);
        acc[m][n] = __builtin_amdgcn_mfma_f32_16x16x32_f16(a2[m], b1[n], acc[m][n], 0, 0, 0);
        acc[m][n] = __builtin_amdgcn_mfma_f32_16x16x32_f16(a1[m], b2[n], acc[m][n], 0, 0, 0);
      }
    __syncthreads();  // drains prefetch vmcnt + protects LDS reads
    cur ^= 1;
  }
#undef STAGE

  // epilogue: D mapping col=lane&15, row=4*(lane>>4)+j  (m89-verified)
  const int crow = m0 + wr * 64 + 4 * (lane >> 4);
  const int ccol0 = n0 + wcol * 64 + (lane & 15);
#pragma unroll
  for (int n = 0; n < 4; ++n) {
    const int col = ccol0 + n * 16;
    const float bv = bias[col];
#pragma unroll
    for (int m = 0; m < 4; ++m) {
#pragma unroll
      for (int j = 0; j < 4; ++j) {
        const int row = crow + m * 16 + j;
        if (row < M) {
          float v = acc[m][n][j] * (1.0f / 65536.0f) + bv;
          v = fmaxf(v, 0.0f);
          if (EPI == 1) {
            float sv = v * 256.0f;
            f16 hh = (f16)sv;
            ((f16*)out1)[(size_t)row * 1024 + col] = hh;
            ((f16*)out2)[(size_t)row * 1024 + col] = (f16)(sv - (float)hh);
          } else {
            ((float*)out1)[(size_t)row * 1024 + col] = v;
          }
        }
      }
    }
  }
}

// ---------------------------------------------------------------------------
// Final head: c/r dots (fp32), argmax/scores, per-class delta, box decode+clip
// ---------------------------------------------------------------------------
__device__ __forceinline__ float dot4f(float4 a, float4 b) {
  return a.x * b.x + a.y * b.y + a.z * b.z + a.w * b.w;
}

__global__ __launch_bounds__(256) void head_final(
    const float* __restrict__ v7,
    const float* __restrict__ wc, const float* __restrict__ bc,
    const float* __restrict__ wr, const float* __restrict__ br,
    const float* __restrict__ rois,
    float* __restrict__ outScores, float* __restrict__ outClasses,
    float* __restrict__ outBoxes,
    float* __restrict__ smask, float* __restrict__ wsbox, int* __restrict__ wsval) {
  const int gw = (blockIdx.x * 256 + threadIdx.x) >> 6;
  const int lane = threadIdx.x & 63;
  if (gw >= 8000) return;

  const float4* vr = (const float4*)(v7 + (size_t)gw * 1024);
  float4 x0 = vr[lane], x1 = vr[64 + lane], x2 = vr[128 + lane], x3 = vr[192 + lane];

  float s[20];
#pragma unroll
  for (int o = 0; o < 20; ++o) {
    const float* wrow = (o < 4) ? (wc + o * 1024) : (wr + (o - 4) * 1024);
    const float4* w4 = (const float4*)wrow;
    float a = dot4f(x0, w4[lane]) + dot4f(x1, w4[64 + lane]) +
              dot4f(x2, w4[128 + lane]) + dot4f(x3, w4[192 + lane]);
#pragma unroll
    for (int off = 32; off >= 1; off >>= 1) a += __shfl_xor(a, off);
    s[o] = a + ((o < 4) ? bc[o] : br[o - 4]);
  }

  float best = s[0]; int cls = 0;
  if (s[1] > best) { best = s[1]; cls = 1; }
  if (s[2] > best) { best = s[2]; cls = 2; }
  if (s[3] > best) { best = s[3]; cls = 3; }

  float d0, d1, d2, d3;  // constant indices only (avoid scratch)
  if      (cls == 0) { d0 = s[4];  d1 = s[5];  d2 = s[6];  d3 = s[7];  }
  else if (cls == 1) { d0 = s[8];  d1 = s[9];  d2 = s[10]; d3 = s[11]; }
  else if (cls == 2) { d0 = s[12]; d1 = s[13]; d2 = s[14]; d3 = s[15]; }
  else               { d0 = s[16]; d1 = s[17]; d2 = s[18]; d3 = s[19]; }

  float4 rb = ((const float4*)rois)[gw];
  float w = rb.z - rb.x, h = rb.w - rb.y;
  float cx = rb.x + 0.5f * w, cy = rb.y + 0.5f * h;
  float pcx = cx + d0 * 0.1f * w;
  float pcy = cy + d1 * 0.1f * h;
  float pw = expf(d2 * 0.2f) * w;
  float ph = expf(d3 * 0.2f) * h;
  float bx0 = fminf(fmaxf(pcx - 0.5f * pw, 0.f), 512.f);
  float by0 = fminf(fmaxf(pcy - 0.5f * ph, 0.f), 512.f);
  float bx1 = fminf(fmaxf(pcx + 0.5f * pw, 0.f), 512.f);
  float by1 = fminf(fmaxf(pcy + 0.5f * ph, 0.f), 512.f);

  if (lane == 0) {
    outScores[gw] = best;
    outClasses[gw] = (float)cls;
    outBoxes[gw * 4 + 0] = bx0;
    outBoxes[gw * 4 + 1] = by0;
    outBoxes[gw * 4 + 2] = bx1;
    outBoxes[gw * 4 + 3] = by1;
    int valid = (cls != 3);
    smask[gw] = valid ? best : -INFINITY;
    wsval[gw] = valid;
    float4 bb; bb.x = bx0; bb.y = by0; bb.z = bx1; bb.w = by1;
    ((float4*)wsbox)[gw] = bb;
  }
}

// ---------------------------------------------------------------------------
// Stable descending rank (== argsort(-s) position), then scatter to sorted arrays
// ---------------------------------------------------------------------------
__global__ __launch_bounds__(256) void rank_kernel(
    const float* __restrict__ smask, const float* __restrict__ bx,
    const int* __restrict__ valid,
    int* __restrict__ order, float* __restrict__ sboxes, int* __restrict__ svalid) {
  __shared__ __align__(16) float sS[8000];
  const int tid = threadIdx.x;
  for (int i = tid; i < 8000; i += 256) sS[i] = smask[i];
  __syncthreads();
  const int i = blockIdx.x * 256 + tid;
  if (i >= 8000) return;
  const float si = sS[i];
  int cnt = 0;
  const float4* s4p = (const float4*)sS;
  for (int j4 = 0; j4 < 2000; ++j4) {
    float4 s4 = s4p[j4];
    int jb = j4 * 4;
    cnt += (s4.x > si) || (s4.x == si && (jb + 0) < i);
    cnt += (s4.y > si) || (s4.y == si && (jb + 1) < i);
    cnt += (s4.z > si) || (s4.z == si && (jb + 2) < i);
    cnt += (s4.w > si) || (s4.w == si && (jb + 3) < i);
  }
  order[cnt] = i;
  svalid[cnt] = valid[i];
  ((float4*)sboxes)[cnt] = ((const float4*)bx)[i];
}

// ---------------------------------------------------------------------------
// Suppression bitmask matrix in SORTED order: M[row][w] bit j = (IoU>0.2 && col>row)
// row stride 128 u64. Also writes coalesced diagonal blocks Mdiag[t*64+lane].
// ---------------------------------------------------------------------------
__global__ void iou_matrix(const float* __restrict__ sboxes, u64* __restrict__ M,
                           u64* __restrict__ Mdiag) {
  const int t = blockIdx.y, w = blockIdx.x;
  if (w < t) return;
  const int lane = threadIdx.x;
  __shared__ __align__(16) float cb[64 * 4];
  ((float4*)cb)[lane] = ((const float4*)sboxes)[w * 64 + lane];
  __syncthreads();
  const int ri = t * 64 + lane;
  float4 rb = ((const float4*)sboxes)[ri];
  const float ra = (rb.z - rb.x) * (rb.w - rb.y);
  u64 bits = 0;
  for (int j = 0; j < 64; ++j) {
    float4 c = ((float4*)cb)[j];
    float x1 = fmaxf(rb.x, c.x), y1 = fmaxf(rb.y, c.y);
    float x2 = fminf(rb.z, c.z), y2 = fminf(rb.w, c.w);
    float inter = fmaxf(x2 - x1, 0.f) * fmaxf(y2 - y1, 0.f);
    float ca = (c.z - c.x) * (c.w - c.y);
    float iou = inter / (ra + ca - inter + 1e-8f);
    int gc = w * 64 + j;
    if (iou > 0.2f && gc > ri) bits |= (1ULL << j);
  }
  M[(size_t)ri * 128 + w] = bits;
  if (w == t) Mdiag[(size_t)t * 64 + lane] = bits;
}

// ---------------------------------------------------------------------------
// Sequential greedy NMS scan. Single block. Per tile: wave-0 shfl closure
// (exact sequential semantics) over coalesced diag rows, then parallel OR of
// kept rows (shared LDS kept-list, 4-wide independent loads).
// ---------------------------------------------------------------------------
__global__ __launch_bounds__(128) void nms_scan(
    const u64* __restrict__ M, const u64* __restrict__ Mdiag,
    const int* __restrict__ order,
    const int* __restrict__ svalid, float* __restrict__ outKeep) {
  __shared__ u64 acc[126];
  __shared__ u64 rshare;
  __shared__ unsigned char klist[64];
  __shared__ int kcount;
  const int tid = threadIdx.x;
  for (int w = tid; w < 125; w += 128) acc[w] = 0;
  __syncthreads();

  for (int t = 0; t < 125; ++t) {
    if (tid < 64) {  // wave 0: register closure, exact sequential semantics
      u64 myrow = Mdiag[(size_t)t * 64 + tid];  // coalesced
      u64 r = acc[t];
      for (int i = 0; i < 64; ++i) {
        unsigned rlo = (unsigned)__shfl((int)(unsigned)myrow, i);
        unsigned rhi = (unsigned)__shfl((int)(unsigned)(myrow >> 32), i);
        u64 rowi = ((u64)rhi << 32) | (u64)rlo;
        if (!((r >> i) & 1ULL)) r |= rowi;
      }
      if (tid == 0) {
        acc[t] = r;
        rshare = r;
        int c = 0;
        u64 kept = ~r;
        while (kept) { int i = __builtin_ctzll(kept); kept &= kept - 1; klist[c++] = (unsigned char)i; }
        kcount = c;
      }
    }
    __syncthreads();
    const int kc = kcount;
    const int w = t + 1 + tid;
    if (w < 125) {
      u64 a = acc[w];
      const u64* base = M + (size_t)t * 64 * 128 + w;
      int j = 0;
      for (; j + 4 <= kc; j += 4) {  // 4 independent loads -> latency pipelined
        u64 v0 = base[(size_t)klist[j] * 128];
        u64 v1 = base[(size_t)klist[j + 1] * 128];
        u64 v2 = base[(size_t)klist[j + 2] * 128];
        u64 v3 = base[(size_t)klist[j + 3] * 128];
        a |= (v0 | v1) | (v2 | v3);
      }
      for (; j < kc; ++j) a |= base[(size_t)klist[j] * 128];
      acc[w] = a;
    }
    __syncthreads();
  }

  for (int p = tid; p < 8000; p += 128) {
    int removed = (int)((acc[p >> 6] >> (p & 63)) & 1ULL);
    float kv = (!removed && svalid[p]) ? 1.0f : 0.0f;
    outKeep[order[p]] = kv;
  }
}

// ---------------------------------------------------------------------------
extern "C" void kernel_launch(void* const* d_in, const int* in_sizes, int n_in,
                              void* d_out, int out_size, void* d_ws, size_t ws_size,
                              hipStream_t stream) {
  const float* F    = (const float*)d_in[0];
  const float* ROIS = (const float*)d_in[1];
  const float* W6   = (const float*)d_in[2];
  const float* B6   = (const float*)d_in[3];
  const float* W7   = (const float*)d_in[4];
  const float* B7   = (const float*)d_in[5];
  const float* WC   = (const float*)d_in[6];
  const float* BC   = (const float*)d_in[7];
  const float* WR   = (const float*)d_in[8];
  const float* BR   = (const float*)d_in[9];

  const size_t N = 8000, D = 12544, H = 1024;
  char* ws = (char*)d_ws;
  size_t off = 0;
  auto alloc = [&](size_t bytes) -> void* {
    void* p = (void*)(ws + off);
    off += (bytes + 255) & ~(size_t)255;
    return p;
  };
  f16*   A1    = (f16*)alloc(N * D * 2);
  f16*   A2    = (f16*)alloc(N * D * 2);
  f16*   B1w   = (f16*)alloc(H * D * 2);
  f16*   B2w   = (f16*)alloc(H * D * 2);
  f16*   V61   = (f16*)alloc(N * H * 2);
  f16*   V62   = (f16*)alloc(N * H * 2);
  f16*   W71   = (f16*)alloc(H * H * 2);
  f16*   W72   = (f16*)alloc(H * H * 2);
  float* V7    = (float*)alloc(N * H * 4);
  float* SMASK = (float*)alloc(N * 4);
  float* WSBOX = (float*)alloc(N * 16);
  int*   WSVAL = (int*)alloc(N * 4);
  int*   ORDER = (int*)alloc(N * 4);
  float* SBOX  = (float*)alloc(N * 16);
  int*   SVAL  = (int*)alloc(N * 4);
  u64*   MM    = (u64*)alloc(N * 128 * 8);
  u64*   MDIAG = (u64*)alloc(125 * 64 * 8);

  float* outScores  = (float*)d_out;
  float* outClasses = (float*)d_out + 8000;
  float* outBoxes   = (float*)d_out + 16000;
  float* outKeep    = (float*)d_out + 48000;

  split_kernel<<<2048, 256, 0, stream>>>(F, A1, A2, (long)(N * D / 4), 256.0f);
  split_kernel<<<1024, 256, 0, stream>>>(W6, B1w, B2w, (long)(H * D / 4), 256.0f);
  split_kernel<<<256, 256, 0, stream>>>(W7, W71, W72, (long)(H * H / 4), 256.0f);

  gemm_split<1><<<dim3(8, 63), 256, 0, stream>>>(A1, A2, B1w, B2w, B6, V61, V62, 8000, 12544);
  gemm_split<2><<<dim3(8, 63), 256, 0, stream>>>(V61, V62, W71, W72, B7, V7, nullptr, 8000, 1024);

  head_final<<<2000, 256, 0, stream>>>(V7, WC, BC, WR, BR, ROIS,
                                       outScores, outClasses, outBoxes,
                                       SMASK, WSBOX, WSVAL);
  rank_kernel<<<32, 256, 0, stream>>>(SMASK, WSBOX, WSVAL, ORDER, SBOX, SVAL);
  iou_matrix<<<dim3(125, 125), 64, 0, stream>>>(SBOX, MM, MDIAG);
  nms_scan<<<1, 128, 0, stream>>>(MM, MDIAG, ORDER, SVAL, outKeep);
}

// Round 3
// 1452.326 us; speedup vs baseline: 1.1998x; 1.0741x over previous
//
#include <hip/hip_runtime.h>
#include <hip/hip_fp16.h>
#include <math.h>

typedef _Float16 f16;
typedef _Float16 f16x4 __attribute__((ext_vector_type(4)));
typedef _Float16 f16x8 __attribute__((ext_vector_type(8)));
typedef float f32x4 __attribute__((ext_vector_type(4)));
typedef unsigned long long u64;

// async global->LDS, 16B per lane; LDS dest must be wave-uniform base (HW adds lane*16)
#define GLD16(g, s) __builtin_amdgcn_global_load_lds( \
    (const __attribute__((address_space(1))) void*)(g), \
    (__attribute__((address_space(3))) void*)(s), 16, 0, 0)

// ---------------------------------------------------------------------------
// split fp32 -> (hi, lo) f16 pair, pre-scaled by `scale` (=256). Used for
// weights only now (F's split is fused into gemm_split<.,1>).
// ---------------------------------------------------------------------------
__global__ __launch_bounds__(256) void split_kernel(const float* __restrict__ src,
                                                    f16* __restrict__ hi,
                                                    f16* __restrict__ lo,
                                                    long n4, float scale) {
  long stride = (long)gridDim.x * blockDim.x;
  for (long i = (long)blockIdx.x * blockDim.x + threadIdx.x; i < n4; i += stride) {
    float4 v = ((const float4*)src)[i];
    f16x4 h, l;
    float e0 = v.x * scale; f16 h0 = (f16)e0; h[0] = h0; l[0] = (f16)(e0 - (float)h0);
    float e1 = v.y * scale; f16 h1 = (f16)e1; h[1] = h1; l[1] = (f16)(e1 - (float)h1);
    float e2 = v.z * scale; f16 h2 = (f16)e2; h[2] = h2; l[2] = (f16)(e2 - (float)h2);
    float e3 = v.w * scale; f16 h3 = (f16)e3; h[3] = h3; l[3] = (f16)(e3 - (float)h3);
    ((f16x4*)hi)[i] = h;
    ((f16x4*)lo)[i] = l;
  }
}

// ---------------------------------------------------------------------------
// Split-precision GEMM, 3-product (hi*hi + lo*hi + hi*lo).
// AFP32=1: A is raw fp32; staged fp32 in LDS (chunk-XOR swizzled), converted
//          to (hi,lo)*256 f16 fragments in registers (fused split: saves the
//          800MB split round-trip for F).
// AFP32=0: A pre-split f16 hi/lo (chunk-XOR swizzled).
// 128x128 tile, BK=32, 4 waves, double-buffered LDS (64 KB).
// ---------------------------------------------------------------------------
template<int EPI, int AFP32>
__global__ __launch_bounds__(256) void gemm_split(
    const void* __restrict__ Av1, const void* __restrict__ Av2,
    const f16* __restrict__ B1, const f16* __restrict__ B2,
    const float* __restrict__ bias,
    void* __restrict__ out1, void* __restrict__ out2,
    const int M, const int K) {
  __shared__ __align__(16) char sA[2][16384];           // fp32 tile OR f16 hi+lo tiles
  __shared__ __align__(16) f16 sB1[2][4096], sB2[2][4096];
  const int tid = threadIdx.x;
  const int lane = tid & 63;
  const int wid = tid >> 6;
  const int wr = wid >> 1, wcol = wid & 1;
  const int m0 = blockIdx.y * 128;
  const int n0 = blockIdx.x * 128;

  f32x4 acc[4][4];
#pragma unroll
  for (int m = 0; m < 4; ++m)
#pragma unroll
    for (int n = 0; n < 4; ++n) acc[m][n] = (f32x4){0.f, 0.f, 0.f, 0.f};

  // ---- B staging addresses (f16 chunk-XOR, unchanged from r2; 0 conflicts) ----
  const int rq = tid >> 2;                                  // 0..63
  const int cg = (((tid & 3) ^ ((rq >> 1) & 3)) * 8);       // swizzled k-offset
  const int rb0 = n0 + rq, rb1 = n0 + 64 + rq;              // N=1024 always full
  const f16* gB1q0 = B1 + (size_t)rb0 * K + cg;
  const f16* gB1q1 = B1 + (size_t)rb1 * K + cg;
  const f16* gB2q0 = B2 + (size_t)rb0 * K + cg;
  const f16* gB2q1 = B2 + (size_t)rb1 * K + cg;
  const int du = wid * 512;   // f16-elem wave base

  // ---- A staging addresses ----
  // AFP32=1: fp32 tile 128x32. LDS elem e=q*256+tid -> row=e>>3, slot=tid&7.
  //          global chunk = slot ^ (row&7); coalesced per 128B row segment.
  const float* gAf[4];
  if (AFP32) {
    const float* Af = (const float*)Av1;
#pragma unroll
    for (int q = 0; q < 4; ++q) {
      int rowg = m0 + q * 32 + (tid >> 3);
      if (rowg > M - 1) rowg = M - 1;
      const int chunkg = (tid & 7) ^ ((tid >> 3) & 7);
      gAf[q] = Af + (size_t)rowg * K + chunkg * 4;
    }
  }
  // AFP32=0: f16 hi/lo pair, same scheme as B.
  const f16 *gA1q0 = nullptr, *gA1q1 = nullptr, *gA2q0 = nullptr, *gA2q1 = nullptr;
  if (!AFP32) {
    int ra0 = m0 + rq;      if (ra0 > M - 1) ra0 = M - 1;
    int ra1 = m0 + 64 + rq; if (ra1 > M - 1) ra1 = M - 1;
    gA1q0 = (const f16*)Av1 + (size_t)ra0 * K + cg;
    gA1q1 = (const f16*)Av1 + (size_t)ra1 * K + cg;
    gA2q0 = (const f16*)Av2 + (size_t)ra0 * K + cg;
    gA2q1 = (const f16*)Av2 + (size_t)ra1 * K + cg;
  }

  const int arow = wr * 64 + (lane & 15);
  const int brow = wcol * 64 + (lane & 15);
  const int kcA = (((lane >> 4) ^ ((arow >> 1) & 3)) * 8);   // f16-A read swizzle
  const int kcB = (((lane >> 4) ^ ((brow >> 1) & 3)) * 8);
  const int pA0 = (((lane >> 4) * 2)     ^ (arow & 7)) * 4;  // fp32-A read swizzle
  const int pA1 = (((lane >> 4) * 2 + 1) ^ (arow & 7)) * 4;

  const int nt = K / 32;

#define STAGE(buf, kt)                                            \
  do {                                                            \
    if (AFP32) {                                                  \
      float* db = (float*)sA[buf];                                \
      GLD16(gAf[0] + (kt), db + 0 * 1024 + wid * 256);            \
      GLD16(gAf[1] + (kt), db + 1 * 1024 + wid * 256);            \
      GLD16(gAf[2] + (kt), db + 2 * 1024 + wid * 256);            \
      GLD16(gAf[3] + (kt), db + 3 * 1024 + wid * 256);            \
    } else {                                                      \
      f16* d1 = (f16*)sA[buf];                                    \
      f16* d2 = d1 + 4096;                                        \
      GLD16(gA1q0 + (kt), d1 + du);                               \
      GLD16(gA1q1 + (kt), d1 + 2048 + du);                        \
      GLD16(gA2q0 + (kt), d2 + du);                               \
      GLD16(gA2q1 + (kt), d2 + 2048 + du);                        \
    }                                                             \
    GLD16(gB1q0 + (kt), &sB1[buf][du]);                           \
    GLD16(gB1q1 + (kt), &sB1[buf][2048 + du]);                    \
    GLD16(gB2q0 + (kt), &sB2[buf][du]);                           \
    GLD16(gB2q1 + (kt), &sB2[buf][2048 + du]);                    \
  } while (0)

  STAGE(0, 0);
  __syncthreads();
  int cur = 0;

  for (int t = 0; t < nt; ++t) {
    if (t + 1 < nt) STAGE(cur ^ 1, (t + 1) * 32);  // prefetch BEFORE compute

    f16x8 a1[4], a2[4], b1[4], b2[4];
    if (AFP32) {
      const float* sf = (const float*)sA[cur];
#pragma unroll
      for (int m = 0; m < 4; ++m) {
        const float* rp = sf + (arow + m * 16) * 32;
        f32x4 u = *(const f32x4*)(rp + pA0);   // logical cols 8k..8k+3
        f32x4 v = *(const f32x4*)(rp + pA1);   // logical cols 8k+4..8k+7
        f16x8 h, l;
#pragma unroll
        for (int j = 0; j < 4; ++j) {
          float e = u[j] * 256.0f; f16 hh = (f16)e;
          h[j] = hh; l[j] = (f16)(e - (float)hh);
        }
#pragma unroll
        for (int j = 0; j < 4; ++j) {
          float e = v[j] * 256.0f; f16 hh = (f16)e;
          h[4 + j] = hh; l[4 + j] = (f16)(e - (float)hh);
        }
        a1[m] = h; a2[m] = l;
      }
    } else {
      const f16* s1 = (const f16*)sA[cur];
      const f16* s2 = s1 + 4096;
#pragma unroll
      for (int m = 0; m < 4; ++m) {
        a1[m] = *(const f16x8*)&s1[(arow + m * 16) * 32 + kcA];
        a2[m] = *(const f16x8*)&s2[(arow + m * 16) * 32 + kcA];
      }
    }
#pragma unroll
    for (int n = 0; n < 4; ++n) {
      b1[n] = *(const f16x8*)&sB1[cur][(brow + n * 16) * 32 + kcB];
      b2[n] = *(const f16x8*)&sB2[cur][(brow + n * 16) * 32 + kcB];
    }
#pragma unroll
    for (int m = 0; m < 4; ++m)
#pragma unroll
      for (int n = 0; n < 4; ++n) {
        acc[m][n] = __builtin_amdgcn_mfma_f32_16x16x32_f16(a1[m], b1[n], acc[m][n], 0, 0, 0);
        acc[m][n] = __builtin_amdgcn_mfma_f32_16x16x32_f16(a2[m], b1[n], acc[m][n], 0, 0, 0);
        acc[m][n] = __builtin_amdgcn_mfma_f32_16x16x32_f16(a1[m], b2[n], acc[m][n], 0, 0, 0);
      }
    __syncthreads();  // drains prefetch vmcnt + protects LDS
    cur ^= 1;
  }
#undef STAGE

  // epilogue: D mapping col=lane&15, row=4*(lane>>4)+j
  const int crow = m0 + wr * 64 + 4 * (lane >> 4);
  const int ccol0 = n0 + wcol * 64 + (lane & 15);
#pragma unroll
  for (int n = 0; n < 4; ++n) {
    const int col = ccol0 + n * 16;
    const float bv = bias[col];
#pragma unroll
    for (int m = 0; m < 4; ++m) {
#pragma unroll
      for (int j = 0; j < 4; ++j) {
        const int row = crow + m * 16 + j;
        if (row < M) {
          float v = acc[m][n][j] * (1.0f / 65536.0f) + bv;
          v = fmaxf(v, 0.0f);
          if (EPI == 1) {
            float sv = v * 256.0f;
            f16 hh = (f16)sv;
            ((f16*)out1)[(size_t)row * 1024 + col] = hh;
            ((f16*)out2)[(size_t)row * 1024 + col] = (f16)(sv - (float)hh);
          } else {
            ((float*)out1)[(size_t)row * 1024 + col] = v;
          }
        }
      }
    }
  }
}

// ---------------------------------------------------------------------------
// Final head: c/r dots (fp32), argmax/scores, per-class delta, box decode+clip
// ---------------------------------------------------------------------------
__device__ __forceinline__ float dot4f(float4 a, float4 b) {
  return a.x * b.x + a.y * b.y + a.z * b.z + a.w * b.w;
}

__global__ __launch_bounds__(256) void head_final(
    const float* __restrict__ v7,
    const float* __restrict__ wc, const float* __restrict__ bc,
    const float* __restrict__ wr, const float* __restrict__ br,
    const float* __restrict__ rois,
    float* __restrict__ outScores, float* __restrict__ outClasses,
    float* __restrict__ outBoxes,
    float* __restrict__ smask, float* __restrict__ wsbox, int* __restrict__ wsval) {
  const int gw = (blockIdx.x * 256 + threadIdx.x) >> 6;
  const int lane = threadIdx.x & 63;
  if (gw >= 8000) return;

  const float4* vr = (const float4*)(v7 + (size_t)gw * 1024);
  float4 x0 = vr[lane], x1 = vr[64 + lane], x2 = vr[128 + lane], x3 = vr[192 + lane];

  float s[20];
#pragma unroll
  for (int o = 0; o < 20; ++o) {
    const float* wrow = (o < 4) ? (wc + o * 1024) : (wr + (o - 4) * 1024);
    const float4* w4 = (const float4*)wrow;
    float a = dot4f(x0, w4[lane]) + dot4f(x1, w4[64 + lane]) +
              dot4f(x2, w4[128 + lane]) + dot4f(x3, w4[192 + lane]);
#pragma unroll
    for (int off = 32; off >= 1; off >>= 1) a += __shfl_xor(a, off);
    s[o] = a + ((o < 4) ? bc[o] : br[o - 4]);
  }

  float best = s[0]; int cls = 0;
  if (s[1] > best) { best = s[1]; cls = 1; }
  if (s[2] > best) { best = s[2]; cls = 2; }
  if (s[3] > best) { best = s[3]; cls = 3; }

  float d0, d1, d2, d3;  // constant indices only (avoid scratch)
  if      (cls == 0) { d0 = s[4];  d1 = s[5];  d2 = s[6];  d3 = s[7];  }
  else if (cls == 1) { d0 = s[8];  d1 = s[9];  d2 = s[10]; d3 = s[11]; }
  else if (cls == 2) { d0 = s[12]; d1 = s[13]; d2 = s[14]; d3 = s[15]; }
  else               { d0 = s[16]; d1 = s[17]; d2 = s[18]; d3 = s[19]; }

  float4 rb = ((const float4*)rois)[gw];
  float w = rb.z - rb.x, h = rb.w - rb.y;
  float cx = rb.x + 0.5f * w, cy = rb.y + 0.5f * h;
  float pcx = cx + d0 * 0.1f * w;
  float pcy = cy + d1 * 0.1f * h;
  float pw = expf(d2 * 0.2f) * w;
  float ph = expf(d3 * 0.2f) * h;
  float bx0 = fminf(fmaxf(pcx - 0.5f * pw, 0.f), 512.f);
  float by0 = fminf(fmaxf(pcy - 0.5f * ph, 0.f), 512.f);
  float bx1 = fminf(fmaxf(pcx + 0.5f * pw, 0.f), 512.f);
  float by1 = fminf(fmaxf(pcy + 0.5f * ph, 0.f), 512.f);

  if (lane == 0) {
    outScores[gw] = best;
    outClasses[gw] = (float)cls;
    outBoxes[gw * 4 + 0] = bx0;
    outBoxes[gw * 4 + 1] = by0;
    outBoxes[gw * 4 + 2] = bx1;
    outBoxes[gw * 4 + 3] = by1;
    int valid = (cls != 3);
    smask[gw] = valid ? best : -INFINITY;
    wsval[gw] = valid;
    float4 bb; bb.x = bx0; bb.y = by0; bb.z = bx1; bb.w = by1;
    ((float4*)wsbox)[gw] = bb;
  }
}

// ---------------------------------------------------------------------------
// Stable descending rank (== argsort(-s) position), then scatter to sorted arrays
// ---------------------------------------------------------------------------
__global__ __launch_bounds__(256) void rank_kernel(
    const float* __restrict__ smask, const float* __restrict__ bx,
    const int* __restrict__ valid,
    int* __restrict__ order, float* __restrict__ sboxes, int* __restrict__ svalid) {
  __shared__ __align__(16) float sS[8000];
  const int tid = threadIdx.x;
  for (int i = tid; i < 8000; i += 256) sS[i] = smask[i];
  __syncthreads();
  const int i = blockIdx.x * 256 + tid;
  if (i >= 8000) return;
  const float si = sS[i];
  int cnt = 0;
  const float4* s4p = (const float4*)sS;
  for (int j4 = 0; j4 < 2000; ++j4) {
    float4 s4 = s4p[j4];
    int jb = j4 * 4;
    cnt += (s4.x > si) || (s4.x == si && (jb + 0) < i);
    cnt += (s4.y > si) || (s4.y == si && (jb + 1) < i);
    cnt += (s4.z > si) || (s4.z == si && (jb + 2) < i);
    cnt += (s4.w > si) || (s4.w == si && (jb + 3) < i);
  }
  order[cnt] = i;
  svalid[cnt] = valid[i];
  ((float4*)sboxes)[cnt] = ((const float4*)bx)[i];
}

// ---------------------------------------------------------------------------
// Suppression bitmask matrix in SORTED order. Skips tile-pairs where either
// tile is entirely invalid (sorted: invalid iff first row invalid) — those
// bits can only affect masked-out boxes. nms_scan uses the same predicate,
// so no unwritten (poisoned) M word is ever read.
// ---------------------------------------------------------------------------
__global__ void iou_matrix(const float* __restrict__ sboxes, u64* __restrict__ M,
                           u64* __restrict__ Mdiag, const int* __restrict__ svalid) {
  const int t = blockIdx.y, w = blockIdx.x;
  if (w < t) return;
  if (svalid[t * 64] == 0 || svalid[w * 64] == 0) return;
  const int lane = threadIdx.x;
  __shared__ __align__(16) float cb[64 * 4];
  ((float4*)cb)[lane] = ((const float4*)sboxes)[w * 64 + lane];
  __syncthreads();
  const int ri = t * 64 + lane;
  float4 rb = ((const float4*)sboxes)[ri];
  const float ra = (rb.z - rb.x) * (rb.w - rb.y);
  u64 bits = 0;
  for (int j = 0; j < 64; ++j) {
    float4 c = ((float4*)cb)[j];
    float x1 = fmaxf(rb.x, c.x), y1 = fmaxf(rb.y, c.y);
    float x2 = fminf(rb.z, c.z), y2 = fminf(rb.w, c.w);
    float inter = fmaxf(x2 - x1, 0.f) * fmaxf(y2 - y1, 0.f);
    float ca = (c.z - c.x) * (c.w - c.y);
    float iou = inter / (ra + ca - inter + 1e-8f);
    int gc = w * 64 + j;
    if (iou > 0.2f && gc > ri) bits |= (1ULL << j);
  }
  M[(size_t)ri * 128 + w] = bits;
  if (w == t) Mdiag[(size_t)t * 64 + lane] = bits;
}

// ---------------------------------------------------------------------------
// Sequential greedy NMS scan, truncated to tiles containing valid boxes.
// ---------------------------------------------------------------------------
__global__ __launch_bounds__(128) void nms_scan(
    const u64* __restrict__ M, const u64* __restrict__ Mdiag,
    const int* __restrict__ order,
    const int* __restrict__ svalid, float* __restrict__ outKeep) {
  __shared__ u64 acc[126];
  __shared__ u64 rshare;
  __shared__ unsigned char klist[64];
  __shared__ int kcount;
  __shared__ int tv[125];
  __shared__ int nvt_s;
  const int tid = threadIdx.x;
  for (int w = tid; w < 125; w += 128) acc[w] = 0;
  if (tid < 125) tv[tid] = svalid[tid * 64];
  __syncthreads();
  if (tid == 0) {
    int c = 0;
    while (c < 125 && tv[c]) ++c;
    nvt_s = c;
  }
  __syncthreads();
  const int nvt = nvt_s;

  for (int t = 0; t < nvt; ++t) {
    if (tid < 64) {  // wave 0: register closure, exact sequential semantics
      u64 myrow = Mdiag[(size_t)t * 64 + tid];  // coalesced
      u64 r = acc[t];
      for (int i = 0; i < 64; ++i) {
        unsigned rlo = (unsigned)__shfl((int)(unsigned)myrow, i);
        unsigned rhi = (unsigned)__shfl((int)(unsigned)(myrow >> 32), i);
        u64 rowi = ((u64)rhi << 32) | (u64)rlo;
        if (!((r >> i) & 1ULL)) r |= rowi;
      }
      if (tid == 0) {
        acc[t] = r;
        rshare = r;
        int c = 0;
        u64 kept = ~r;
        while (kept) { int i = __builtin_ctzll(kept); kept &= kept - 1; klist[c++] = (unsigned char)i; }
        kcount = c;
      }
    }
    __syncthreads();
    const int kc = kcount;
    const int w = t + 1 + tid;
    if (w < nvt) {
      u64 a = acc[w];
      const u64* base = M + (size_t)t * 64 * 128 + w;
      int j = 0;
      for (; j + 4 <= kc; j += 4) {  // 4 independent loads -> latency pipelined
        u64 v0 = base[(size_t)klist[j] * 128];
        u64 v1 = base[(size_t)klist[j + 1] * 128];
        u64 v2 = base[(size_t)klist[j + 2] * 128];
        u64 v3 = base[(size_t)klist[j + 3] * 128];
        a |= (v0 | v1) | (v2 | v3);
      }
      for (; j < kc; ++j) a |= base[(size_t)klist[j] * 128];
      acc[w] = a;
    }
    __syncthreads();
  }

  for (int p = tid; p < 8000; p += 128) {
    int removed = (int)((acc[p >> 6] >> (p & 63)) & 1ULL);
    float kv = (!removed && svalid[p]) ? 1.0f : 0.0f;
    outKeep[order[p]] = kv;
  }
}

// ---------------------------------------------------------------------------
extern "C" void kernel_launch(void* const* d_in, const int* in_sizes, int n_in,
                              void* d_out, int out_size, void* d_ws, size_t ws_size,
                              hipStream_t stream) {
  const float* F    = (const float*)d_in[0];
  const float* ROIS = (const float*)d_in[1];
  const float* W6   = (const float*)d_in[2];
  const float* B6   = (const float*)d_in[3];
  const float* W7   = (const float*)d_in[4];
  const float* B7   = (const float*)d_in[5];
  const float* WC   = (const float*)d_in[6];
  const float* BC   = (const float*)d_in[7];
  const float* WR   = (const float*)d_in[8];
  const float* BR   = (const float*)d_in[9];

  const size_t N = 8000, D = 12544, H = 1024;
  char* ws = (char*)d_ws;
  size_t off = 0;
  auto alloc = [&](size_t bytes) -> void* {
    void* p = (void*)(ws + off);
    off += (bytes + 255) & ~(size_t)255;
    return p;
  };
  f16*   B1w   = (f16*)alloc(H * D * 2);
  f16*   B2w   = (f16*)alloc(H * D * 2);
  f16*   V61   = (f16*)alloc(N * H * 2);
  f16*   V62   = (f16*)alloc(N * H * 2);
  f16*   W71   = (f16*)alloc(H * H * 2);
  f16*   W72   = (f16*)alloc(H * H * 2);
  float* V7    = (float*)alloc(N * H * 4);
  float* SMASK = (float*)alloc(N * 4);
  float* WSBOX = (float*)alloc(N * 16);
  int*   WSVAL = (int*)alloc(N * 4);
  int*   ORDER = (int*)alloc(N * 4);
  float* SBOX  = (float*)alloc(N * 16);
  int*   SVAL  = (int*)alloc(N * 4);
  u64*   MM    = (u64*)alloc(N * 128 * 8);
  u64*   MDIAG = (u64*)alloc(125 * 64 * 8);

  float* outScores  = (float*)d_out;
  float* outClasses = (float*)d_out + 8000;
  float* outBoxes   = (float*)d_out + 16000;
  float* outKeep    = (float*)d_out + 48000;

  split_kernel<<<1024, 256, 0, stream>>>(W6, B1w, B2w, (long)(H * D / 4), 256.0f);
  split_kernel<<<256, 256, 0, stream>>>(W7, W71, W72, (long)(H * H / 4), 256.0f);

  gemm_split<1, 1><<<dim3(8, 63), 256, 0, stream>>>(F, nullptr, B1w, B2w, B6, V61, V62, 8000, 12544);
  gemm_split<2, 0><<<dim3(8, 63), 256, 0, stream>>>(V61, V62, W71, W72, B7, V7, nullptr, 8000, 1024);

  head_final<<<2000, 256, 0, stream>>>(V7, WC, BC, WR, BR, ROIS,
                                       outScores, outClasses, outBoxes,
                                       SMASK, WSBOX, WSVAL);
  rank_kernel<<<32, 256, 0, stream>>>(SMASK, WSBOX, WSVAL, ORDER, SBOX, SVAL);
  iou_matrix<<<dim3(125, 125), 64, 0, stream>>>(SBOX, MM, MDIAG, SVAL);
  nms_scan<<<1, 128, 0, stream>>>(MM, MDIAG, ORDER, SVAL, outKeep);
}

// Round 4
// 1403.137 us; speedup vs baseline: 1.2418x; 1.0351x over previous
//
#include <hip/hip_runtime.h>
#include <hip/hip_fp16.h>
#include <math.h>

typedef _Float16 f16;
typedef _Float16 f16x4 __attribute__((ext_vector_type(4)));
typedef _Float16 f16x8 __attribute__((ext_vector_type(8)));
typedef float f32x4 __attribute__((ext_vector_type(4)));
typedef unsigned long long u64;

// async global->LDS, 16B per lane; LDS dest must be wave-uniform base (HW adds lane*16)
#define GLD16(g, s) __builtin_amdgcn_global_load_lds( \
    (const __attribute__((address_space(1))) void*)(g), \
    (__attribute__((address_space(3))) void*)(s), 16, 0, 0)

// ---------------------------------------------------------------------------
// split fp32 -> (hi, lo) f16 pair, pre-scaled by `scale` (=256). Weights only.
// ---------------------------------------------------------------------------
__global__ __launch_bounds__(256) void split_kernel(const float* __restrict__ src,
                                                    f16* __restrict__ hi,
                                                    f16* __restrict__ lo,
                                                    long n4, float scale) {
  long stride = (long)gridDim.x * blockDim.x;
  for (long i = (long)blockIdx.x * blockDim.x + threadIdx.x; i < n4; i += stride) {
    float4 v = ((const float4*)src)[i];
    f16x4 h, l;
    float e0 = v.x * scale; f16 h0 = (f16)e0; h[0] = h0; l[0] = (f16)(e0 - (float)h0);
    float e1 = v.y * scale; f16 h1 = (f16)e1; h[1] = h1; l[1] = (f16)(e1 - (float)h1);
    float e2 = v.z * scale; f16 h2 = (f16)e2; h[2] = h2; l[2] = (f16)(e2 - (float)h2);
    float e3 = v.w * scale; f16 h3 = (f16)e3; h[3] = h3; l[3] = (f16)(e3 - (float)h3);
    ((f16x4*)hi)[i] = h;
    ((f16x4*)lo)[i] = l;
  }
}

// ---------------------------------------------------------------------------
// Split-precision GEMM, 3-product (hi*hi + lo*hi + hi*lo).
// 256x128 tile, BK=32, 8 waves (512 thr), TRIPLE-buffered LDS (144 KB),
// prefetch depth 2, counted vmcnt(6) (T3+T4): one raw s_barrier per K-step,
// loads stay in flight across it. 6 GLD16/thread/K-step in both variants.
// Safety: at barrier@t every wave has passed its own vmcnt(6) => all waves'
// STAGE(t) complete; STAGE(t+2) (post-barrier) writes buf[(t+2)%3], whose
// last readers (iter t-1) precede barrier@t.
// ---------------------------------------------------------------------------
template<int EPI, int AFP32>
__global__ __launch_bounds__(512) void gemm_split(
    const void* __restrict__ Av1, const void* __restrict__ Av2,
    const f16* __restrict__ B1, const f16* __restrict__ B2,
    const float* __restrict__ bias,
    void* __restrict__ out1, void* __restrict__ out2,
    const int M, const int K) {
  // per buffer: A 32 KB (fp32 256x32 OR f16 hi+lo 2x256x32) + B1 8 KB + B2 8 KB
  __shared__ __align__(16) char smem[3][49152];
  const int tid = threadIdx.x;           // 0..511
  const int lane = tid & 63;
  const int wid = tid >> 6;              // 0..7
  const int wr = wid >> 1, wcol = wid & 1;
  const int m0 = blockIdx.y * 256;
  const int n0 = blockIdx.x * 128;

  f32x4 acc[4][4];
#pragma unroll
  for (int m = 0; m < 4; ++m)
#pragma unroll
    for (int n = 0; n < 4; ++n) acc[m][n] = (f32x4){0.f, 0.f, 0.f, 0.f};

  // ---- B staging: 128x32 f16 per array; 1 GLD16/thread/array ----
  const int rq = tid >> 2;                                  // 0..127 (row)
  const int cg = (((tid & 3) ^ ((tid >> 3) & 3)) * 8);      // swizzled k-offset
  const f16* gB1 = B1 + (size_t)(n0 + rq) * K + cg;
  const f16* gB2 = B2 + (size_t)(n0 + rq) * K + cg;

  // ---- A staging ----
  const float* gAf[4];                     // AFP32: fp32 256x32, 4 GLD16/thread
  if (AFP32) {
    const float* Af = (const float*)Av1;
#pragma unroll
    for (int q = 0; q < 4; ++q) {
      int rowg = m0 + q * 64 + (tid >> 3);
      if (rowg > M - 1) rowg = M - 1;
      const int chunkg = (tid & 7) ^ ((tid >> 3) & 7);
      gAf[q] = Af + (size_t)rowg * K + chunkg * 4;
    }
  }
  const f16 *gA1q0 = nullptr, *gA1q1 = nullptr, *gA2q0 = nullptr, *gA2q1 = nullptr;
  if (!AFP32) {                            // f16 hi/lo 256x32 each, 2+2 GLD16/thread
    int ra0 = m0 + (tid >> 2);       if (ra0 > M - 1) ra0 = M - 1;
    int ra1 = m0 + 128 + (tid >> 2); if (ra1 > M - 1) ra1 = M - 1;
    gA1q0 = (const f16*)Av1 + (size_t)ra0 * K + cg;
    gA1q1 = (const f16*)Av1 + (size_t)ra1 * K + cg;
    gA2q0 = (const f16*)Av2 + (size_t)ra0 * K + cg;
    gA2q1 = (const f16*)Av2 + (size_t)ra1 * K + cg;
  }

  const int arow = wr * 64 + (lane & 15);                    // 0..255 row base
  const int brow = wcol * 64 + (lane & 15);                  // 0..127
  const int kcA = (((lane >> 4) ^ ((arow >> 1) & 3)) * 8);   // f16-A read swizzle
  const int kcB = (((lane >> 4) ^ ((brow >> 1) & 3)) * 8);
  const int pA0 = (((lane >> 4) * 2)     ^ (arow & 7)) * 4;  // fp32-A read swizzle
  const int pA1 = (((lane >> 4) * 2 + 1) ^ (arow & 7)) * 4;

  const int nt = K / 32;

#define STAGE(buf, kt)                                            \
  do {                                                            \
    char* smx = smem[buf];                                        \
    if (AFP32) {                                                  \
      float* db = (float*)smx;                                    \
      GLD16(gAf[0] + (kt), db + 0 * 2048 + wid * 256);            \
      GLD16(gAf[1] + (kt), db + 1 * 2048 + wid * 256);            \
      GLD16(gAf[2] + (kt), db + 2 * 2048 + wid * 256);            \
      GLD16(gAf[3] + (kt), db + 3 * 2048 + wid * 256);            \
    } else {                                                      \
      f16* d1 = (f16*)smx;                                        \
      f16* d2 = d1 + 8192;                                        \
      GLD16(gA1q0 + (kt), d1 + wid * 512);                        \
      GLD16(gA1q1 + (kt), d1 + 4096 + wid * 512);                 \
      GLD16(gA2q0 + (kt), d2 + wid * 512);                        \
      GLD16(gA2q1 + (kt), d2 + 4096 + wid * 512);                 \
    }                                                             \
    GLD16(gB1 + (kt), (f16*)(smx + 32768) + wid * 512);           \
    GLD16(gB2 + (kt), (f16*)(smx + 40960) + wid * 512);           \
  } while (0)

  STAGE(0, 0);
  if (nt > 1) STAGE(1, 32);
  int cur = 0;

  for (int t = 0; t < nt; ++t) {
    // own STAGE(t) complete (6 = STAGE(t+1) still in flight); then barrier
    // makes it a cross-wave guarantee. Never drains to 0 mid-loop.
    if (t + 1 < nt) asm volatile("s_waitcnt vmcnt(6)" ::: "memory");
    else            asm volatile("s_waitcnt vmcnt(0)" ::: "memory");
    asm volatile("s_waitcnt lgkmcnt(0)" ::: "memory");
    __builtin_amdgcn_s_barrier();
    __builtin_amdgcn_sched_barrier(0);

    const char* smx = smem[cur];
    f16x8 a1[4], a2[4], b1[4], b2[4];
    if (AFP32) {
      const float* sf = (const float*)smx;
#pragma unroll
      for (int m = 0; m < 4; ++m) {
        const float* rp = sf + (arow + m * 16) * 32;
        f32x4 u = *(const f32x4*)(rp + pA0);   // logical cols 8k..8k+3
        f32x4 v = *(const f32x4*)(rp + pA1);   // logical cols 8k+4..8k+7
        f16x8 h, l;
#pragma unroll
        for (int j = 0; j < 4; ++j) {
          float e = u[j] * 256.0f; f16 hh = (f16)e;
          h[j] = hh; l[j] = (f16)(e - (float)hh);
        }
#pragma unroll
        for (int j = 0; j < 4; ++j) {
          float e = v[j] * 256.0f; f16 hh = (f16)e;
          h[4 + j] = hh; l[4 + j] = (f16)(e - (float)hh);
        }
        a1[m] = h; a2[m] = l;
      }
    } else {
      const f16* s1 = (const f16*)smx;
      const f16* s2 = s1 + 8192;
#pragma unroll
      for (int m = 0; m < 4; ++m) {
        a1[m] = *(const f16x8*)&s1[(arow + m * 16) * 32 + kcA];
        a2[m] = *(const f16x8*)&s2[(arow + m * 16) * 32 + kcA];
      }
    }
    {
      const f16* sb1 = (const f16*)(smx + 32768);
      const f16* sb2 = (const f16*)(smx + 40960);
#pragma unroll
      for (int n = 0; n < 4; ++n) {
        b1[n] = *(const f16x8*)&sb1[(brow + n * 16) * 32 + kcB];
        b2[n] = *(const f16x8*)&sb2[(brow + n * 16) * 32 + kcB];
      }
    }

    int pre = cur + 2; if (pre >= 3) pre -= 3;
    if (t + 2 < nt) STAGE(pre, (t + 2) * 32);   // depth-2 prefetch, post-barrier

#pragma unroll
    for (int m = 0; m < 4; ++m)
#pragma unroll
      for (int n = 0; n < 4; ++n) {
        acc[m][n] = __builtin_amdgcn_mfma_f32_16x16x32_f16(a1[m], b1[n], acc[m][n], 0, 0, 0);
        acc[m][n] = __builtin_amdgcn_mfma_f32_16x16x32_f16(a2[m], b1[n], acc[m][n], 0, 0, 0);
        acc[m][n] = __builtin_amdgcn_mfma_f32_16x16x32_f16(a1[m], b2[n], acc[m][n], 0, 0, 0);
      }
    ++cur; if (cur >= 3) cur = 0;
  }
#undef STAGE

  // epilogue: D mapping col=lane&15, row=4*(lane>>4)+j
  const int crow = m0 + wr * 64 + 4 * (lane >> 4);
  const int ccol0 = n0 + wcol * 64 + (lane & 15);
#pragma unroll
  for (int n = 0; n < 4; ++n) {
    const int col = ccol0 + n * 16;
    const float bv = bias[col];
#pragma unroll
    for (int m = 0; m < 4; ++m) {
#pragma unroll
      for (int j = 0; j < 4; ++j) {
        const int row = crow + m * 16 + j;
        if (row < M) {
          float v = acc[m][n][j] * (1.0f / 65536.0f) + bv;
          v = fmaxf(v, 0.0f);
          if (EPI == 1) {
            float sv = v * 256.0f;
            f16 hh = (f16)sv;
            ((f16*)out1)[(size_t)row * 1024 + col] = hh;
            ((f16*)out2)[(size_t)row * 1024 + col] = (f16)(sv - (float)hh);
          } else {
            ((float*)out1)[(size_t)row * 1024 + col] = v;
          }
        }
      }
    }
  }
}

// ---------------------------------------------------------------------------
// Final head: c/r dots (fp32), argmax/scores, per-class delta, box decode+clip
// ---------------------------------------------------------------------------
__device__ __forceinline__ float dot4f(float4 a, float4 b) {
  return a.x * b.x + a.y * b.y + a.z * b.z + a.w * b.w;
}

__global__ __launch_bounds__(256) void head_final(
    const float* __restrict__ v7,
    const float* __restrict__ wc, const float* __restrict__ bc,
    const float* __restrict__ wr, const float* __restrict__ br,
    const float* __restrict__ rois,
    float* __restrict__ outScores, float* __restrict__ outClasses,
    float* __restrict__ outBoxes,
    float* __restrict__ smask, float* __restrict__ wsbox, int* __restrict__ wsval) {
  const int gw = (blockIdx.x * 256 + threadIdx.x) >> 6;
  const int lane = threadIdx.x & 63;
  if (gw >= 8000) return;

  const float4* vr = (const float4*)(v7 + (size_t)gw * 1024);
  float4 x0 = vr[lane], x1 = vr[64 + lane], x2 = vr[128 + lane], x3 = vr[192 + lane];

  float s[20];
#pragma unroll
  for (int o = 0; o < 20; ++o) {
    const float* wrow = (o < 4) ? (wc + o * 1024) : (wr + (o - 4) * 1024);
    const float4* w4 = (const float4*)wrow;
    float a = dot4f(x0, w4[lane]) + dot4f(x1, w4[64 + lane]) +
              dot4f(x2, w4[128 + lane]) + dot4f(x3, w4[192 + lane]);
#pragma unroll
    for (int off = 32; off >= 1; off >>= 1) a += __shfl_xor(a, off);
    s[o] = a + ((o < 4) ? bc[o] : br[o - 4]);
  }

  float best = s[0]; int cls = 0;
  if (s[1] > best) { best = s[1]; cls = 1; }
  if (s[2] > best) { best = s[2]; cls = 2; }
  if (s[3] > best) { best = s[3]; cls = 3; }

  float d0, d1, d2, d3;  // constant indices only (avoid scratch)
  if      (cls == 0) { d0 = s[4];  d1 = s[5];  d2 = s[6];  d3 = s[7];  }
  else if (cls == 1) { d0 = s[8];  d1 = s[9];  d2 = s[10]; d3 = s[11]; }
  else if (cls == 2) { d0 = s[12]; d1 = s[13]; d2 = s[14]; d3 = s[15]; }
  else               { d0 = s[16]; d1 = s[17]; d2 = s[18]; d3 = s[19]; }

  float4 rb = ((const float4*)rois)[gw];
  float w = rb.z - rb.x, h = rb.w - rb.y;
  float cx = rb.x + 0.5f * w, cy = rb.y + 0.5f * h;
  float pcx = cx + d0 * 0.1f * w;
  float pcy = cy + d1 * 0.1f * h;
  float pw = expf(d2 * 0.2f) * w;
  float ph = expf(d3 * 0.2f) * h;
  float bx0 = fminf(fmaxf(pcx - 0.5f * pw, 0.f), 512.f);
  float by0 = fminf(fmaxf(pcy - 0.5f * ph, 0.f), 512.f);
  float bx1 = fminf(fmaxf(pcx + 0.5f * pw, 0.f), 512.f);
  float by1 = fminf(fmaxf(pcy + 0.5f * ph, 0.f), 512.f);

  if (lane == 0) {
    outScores[gw] = best;
    outClasses[gw] = (float)cls;
    outBoxes[gw * 4 + 0] = bx0;
    outBoxes[gw * 4 + 1] = by0;
    outBoxes[gw * 4 + 2] = bx1;
    outBoxes[gw * 4 + 3] = by1;
    int valid = (cls != 3);
    smask[gw] = valid ? best : -INFINITY;
    wsval[gw] = valid;
    float4 bb; bb.x = bx0; bb.y = by0; bb.z = bx1; bb.w = by1;
    ((float4*)wsbox)[gw] = bb;
  }
}

// ---------------------------------------------------------------------------
// Stable descending rank (== argsort(-s) position), then scatter to sorted arrays
// ---------------------------------------------------------------------------
__global__ __launch_bounds__(256) void rank_kernel(
    const float* __restrict__ smask, const float* __restrict__ bx,
    const int* __restrict__ valid,
    int* __restrict__ order, float* __restrict__ sboxes, int* __restrict__ svalid) {
  __shared__ __align__(16) float sS[8000];
  const int tid = threadIdx.x;
  for (int i = tid; i < 8000; i += 256) sS[i] = smask[i];
  __syncthreads();
  const int i = blockIdx.x * 256 + tid;
  if (i >= 8000) return;
  const float si = sS[i];
  int cnt = 0;
  const float4* s4p = (const float4*)sS;
  for (int j4 = 0; j4 < 2000; ++j4) {
    float4 s4 = s4p[j4];
    int jb = j4 * 4;
    cnt += (s4.x > si) || (s4.x == si && (jb + 0) < i);
    cnt += (s4.y > si) || (s4.y == si && (jb + 1) < i);
    cnt += (s4.z > si) || (s4.z == si && (jb + 2) < i);
    cnt += (s4.w > si) || (s4.w == si && (jb + 3) < i);
  }
  order[cnt] = i;
  svalid[cnt] = valid[i];
  ((float4*)sboxes)[cnt] = ((const float4*)bx)[i];
}

// ---------------------------------------------------------------------------
// Suppression bitmask matrix in SORTED order; skips all-invalid tile pairs
// (same predicate as nms_scan, so no poisoned M word is ever read).
// ---------------------------------------------------------------------------
__global__ void iou_matrix(const float* __restrict__ sboxes, u64* __restrict__ M,
                           u64* __restrict__ Mdiag, const int* __restrict__ svalid) {
  const int t = blockIdx.y, w = blockIdx.x;
  if (w < t) return;
  if (svalid[t * 64] == 0 || svalid[w * 64] == 0) return;
  const int lane = threadIdx.x;
  __shared__ __align__(16) float cb[64 * 4];
  ((float4*)cb)[lane] = ((const float4*)sboxes)[w * 64 + lane];
  __syncthreads();
  const int ri = t * 64 + lane;
  float4 rb = ((const float4*)sboxes)[ri];
  const float ra = (rb.z - rb.x) * (rb.w - rb.y);
  u64 bits = 0;
  for (int j = 0; j < 64; ++j) {
    float4 c = ((float4*)cb)[j];
    float x1 = fmaxf(rb.x, c.x), y1 = fmaxf(rb.y, c.y);
    float x2 = fminf(rb.z, c.z), y2 = fminf(rb.w, c.w);
    float inter = fmaxf(x2 - x1, 0.f) * fmaxf(y2 - y1, 0.f);
    float ca = (c.z - c.x) * (c.w - c.y);
    float iou = inter / (ra + ca - inter + 1e-8f);
    int gc = w * 64 + j;
    if (iou > 0.2f && gc > ri) bits |= (1ULL << j);
  }
  M[(size_t)ri * 128 + w] = bits;
  if (w == t) Mdiag[(size_t)t * 64 + lane] = bits;
}

// ---------------------------------------------------------------------------
// Sequential greedy NMS scan, truncated to tiles containing valid boxes.
// ---------------------------------------------------------------------------
__global__ __launch_bounds__(128) void nms_scan(
    const u64* __restrict__ M, const u64* __restrict__ Mdiag,
    const int* __restrict__ order,
    const int* __restrict__ svalid, float* __restrict__ outKeep) {
  __shared__ u64 acc[126];
  __shared__ u64 rshare;
  __shared__ unsigned char klist[64];
  __shared__ int kcount;
  __shared__ int tv[125];
  __shared__ int nvt_s;
  const int tid = threadIdx.x;
  for (int w = tid; w < 125; w += 128) acc[w] = 0;
  if (tid < 125) tv[tid] = svalid[tid * 64];
  __syncthreads();
  if (tid == 0) {
    int c = 0;
    while (c < 125 && tv[c]) ++c;
    nvt_s = c;
  }
  __syncthreads();
  const int nvt = nvt_s;

  for (int t = 0; t < nvt; ++t) {
    if (tid < 64) {  // wave 0: register closure, exact sequential semantics
      u64 myrow = Mdiag[(size_t)t * 64 + tid];  // coalesced
      u64 r = acc[t];
      for (int i = 0; i < 64; ++i) {
        unsigned rlo = (unsigned)__shfl((int)(unsigned)myrow, i);
        unsigned rhi = (unsigned)__shfl((int)(unsigned)(myrow >> 32), i);
        u64 rowi = ((u64)rhi << 32) | (u64)rlo;
        if (!((r >> i) & 1ULL)) r |= rowi;
      }
      if (tid == 0) {
        acc[t] = r;
        rshare = r;
        int c = 0;
        u64 kept = ~r;
        while (kept) { int i = __builtin_ctzll(kept); kept &= kept - 1; klist[c++] = (unsigned char)i; }
        kcount = c;
      }
    }
    __syncthreads();
    const int kc = kcount;
    const int w = t + 1 + tid;
    if (w < nvt) {
      u64 a = acc[w];
      const u64* base = M + (size_t)t * 64 * 128 + w;
      int j = 0;
      for (; j + 4 <= kc; j += 4) {  // 4 independent loads -> latency pipelined
        u64 v0 = base[(size_t)klist[j] * 128];
        u64 v1 = base[(size_t)klist[j + 1] * 128];
        u64 v2 = base[(size_t)klist[j + 2] * 128];
        u64 v3 = base[(size_t)klist[j + 3] * 128];
        a |= (v0 | v1) | (v2 | v3);
      }
      for (; j < kc; ++j) a |= base[(size_t)klist[j] * 128];
      acc[w] = a;
    }
    __syncthreads();
  }

  for (int p = tid; p < 8000; p += 128) {
    int removed = (int)((acc[p >> 6] >> (p & 63)) & 1ULL);
    float kv = (!removed && svalid[p]) ? 1.0f : 0.0f;
    outKeep[order[p]] = kv;
  }
}

// ---------------------------------------------------------------------------
extern "C" void kernel_launch(void* const* d_in, const int* in_sizes, int n_in,
                              void* d_out, int out_size, void* d_ws, size_t ws_size,
                              hipStream_t stream) {
  const float* F    = (const float*)d_in[0];
  const float* ROIS = (const float*)d_in[1];
  const float* W6   = (const float*)d_in[2];
  const float* B6   = (const float*)d_in[3];
  const float* W7   = (const float*)d_in[4];
  const float* B7   = (const float*)d_in[5];
  const float* WC   = (const float*)d_in[6];
  const float* BC   = (const float*)d_in[7];
  const float* WR   = (const float*)d_in[8];
  const float* BR   = (const float*)d_in[9];

  const size_t N = 8000, D = 12544, H = 1024;
  char* ws = (char*)d_ws;
  size_t off = 0;
  auto alloc = [&](size_t bytes) -> void* {
    void* p = (void*)(ws + off);
    off += (bytes + 255) & ~(size_t)255;
    return p;
  };
  f16*   B1w   = (f16*)alloc(H * D * 2);
  f16*   B2w   = (f16*)alloc(H * D * 2);
  f16*   V61   = (f16*)alloc(N * H * 2);
  f16*   V62   = (f16*)alloc(N * H * 2);
  f16*   W71   = (f16*)alloc(H * H * 2);
  f16*   W72   = (f16*)alloc(H * H * 2);
  float* V7    = (float*)alloc(N * H * 4);
  float* SMASK = (float*)alloc(N * 4);
  float* WSBOX = (float*)alloc(N * 16);
  int*   WSVAL = (int*)alloc(N * 4);
  int*   ORDER = (int*)alloc(N * 4);
  float* SBOX  = (float*)alloc(N * 16);
  int*   SVAL  = (int*)alloc(N * 4);
  u64*   MM    = (u64*)alloc(N * 128 * 8);
  u64*   MDIAG = (u64*)alloc(125 * 64 * 8);

  float* outScores  = (float*)d_out;
  float* outClasses = (float*)d_out + 8000;
  float* outBoxes   = (float*)d_out + 16000;
  float* outKeep    = (float*)d_out + 48000;

  split_kernel<<<1024, 256, 0, stream>>>(W6, B1w, B2w, (long)(H * D / 4), 256.0f);
  split_kernel<<<256, 256, 0, stream>>>(W7, W71, W72, (long)(H * H / 4), 256.0f);

  gemm_split<1, 1><<<dim3(8, 32), 512, 0, stream>>>(F, nullptr, B1w, B2w, B6, V61, V62, 8000, 12544);
  gemm_split<2, 0><<<dim3(8, 32), 512, 0, stream>>>(V61, V62, W71, W72, B7, V7, nullptr, 8000, 1024);

  head_final<<<2000, 256, 0, stream>>>(V7, WC, BC, WR, BR, ROIS,
                                       outScores, outClasses, outBoxes,
                                       SMASK, WSBOX, WSVAL);
  rank_kernel<<<32, 256, 0, stream>>>(SMASK, WSBOX, WSVAL, ORDER, SBOX, SVAL);
  iou_matrix<<<dim3(125, 125), 64, 0, stream>>>(SBOX, MM, MDIAG, SVAL);
  nms_scan<<<1, 128, 0, stream>>>(MM, MDIAG, ORDER, SVAL, outKeep);
}